// Round 2
// baseline (2357.737 us; speedup 1.0000x reference)
//
#include <hip/hip_runtime.h>

typedef unsigned short u16;
typedef __bf16 bf16x8 __attribute__((ext_vector_type(8)));
typedef float  f32x4  __attribute__((ext_vector_type(4)));

static constexpr int B = 32, N = 4096, KV = 1024, D = 1024, H = 16, MAXF = 4096;

// ---------------- mean over frame tokens (f32 atomic accumulate) [fallback path] ----------------
__global__ __launch_bounds__(256) void mean_kernel(const float* __restrict__ x, float* __restrict__ macc){
  int b = blockIdx.x, ch = blockIdx.y;
  int d0 = threadIdx.x*4;
  const float* p = x + ((size_t)b*N + (size_t)ch*128)*D + d0;
  float a0=0.f,a1=0.f,a2=0.f,a3=0.f;
  for(int k=0;k<128;k++){
    float4 v = *(const float4*)(p + (size_t)k*D);
    a0 += v.x; a1 += v.y; a2 += v.z; a3 += v.w;
  }
  atomicAdd(&macc[b*D + d0 + 0], a0);
  atomicAdd(&macc[b*D + d0 + 1], a1);
  atomicAdd(&macc[b*D + d0 + 2], a2);
  atomicAdd(&macc[b*D + d0 + 3], a3);
}

// ------- convert f32 [b][tok][d] -> bf16 row-major XB and bf16 transposed XT [b][d][tok] -------
// Optionally fuses the per-(b,d) column sum (f32 partials -> atomicAdd) for the frame mean.
__global__ __launch_bounds__(256) void convt_kernel(const float* __restrict__ x,
    u16* __restrict__ xb, u16* __restrict__ xt, float* __restrict__ macc, int Nk){
  int b  = blockIdx.z;
  int t0 = blockIdx.x*64, d0 = blockIdx.y*64;
  __shared__ u16 tile[64][70];        // [tok][d], padded
  __shared__ float rsum[16][64];
  int tid = threadIdx.x;
  int rr = tid>>4, c4 = (tid&15)*4;
  const float* src = x  + ((size_t)b*Nk + t0)*D + d0;
  u16*         xbp = xb + ((size_t)b*Nk + t0)*D + d0;
  float s0=0.f,s1=0.f,s2=0.f,s3=0.f;
  for(int it=0; it<4; it++){
    int r = rr + it*16;
    float4 v = *(const float4*)(src + (size_t)r*D + c4);
    s0+=v.x; s1+=v.y; s2+=v.z; s3+=v.w;
    __bf16 e0=(__bf16)v.x, e1=(__bf16)v.y, e2=(__bf16)v.z, e3=(__bf16)v.w;
    u16 u0=*(u16*)&e0, u1=*(u16*)&e1, u2=*(u16*)&e2, u3=*(u16*)&e3;
    tile[r][c4+0]=u0; tile[r][c4+1]=u1; tile[r][c4+2]=u2; tile[r][c4+3]=u3;
    ushort4 w4; w4.x=u0; w4.y=u1; w4.z=u2; w4.w=u3;
    *(ushort4*)(xbp + (size_t)r*D + c4) = w4;
  }
  if(macc){
    rsum[rr][c4+0]=s0; rsum[rr][c4+1]=s1; rsum[rr][c4+2]=s2; rsum[rr][c4+3]=s3;
  }
  __syncthreads();
  u16* xtp = xt + ((size_t)b*D + d0)*Nk + t0;
  for(int it=0; it<4; it++){
    int dr = rr + it*16;
    ushort4 w4;
    w4.x = tile[c4+0][dr]; w4.y = tile[c4+1][dr];
    w4.z = tile[c4+2][dr]; w4.w = tile[c4+3][dr];
    *(ushort4*)(xtp + (size_t)dr*Nk + c4) = w4;
  }
  if(macc && tid < 64){
    float s = 0.f;
    #pragma unroll
    for(int i2=0;i2<16;i2++) s += rsum[i2][tid];
    atomicAdd(&macc[(size_t)b*D + d0 + tid], s);
  }
}

// ---------------- q init ----------------
__global__ __launch_bounds__(256) void qinit_kernel(const float* __restrict__ macc,
    const float* __restrict__ maxini, const float* __restrict__ qbase, const float* __restrict__ rolew,
    const float* __restrict__ timew, const int* __restrict__ fidx, float* __restrict__ q){
  int b = blockIdx.x;
  int fi = fidx[b]; fi = fi < 0 ? 0 : (fi > MAXF-1 ? MAXF-1 : fi);
  int d0 = threadIdx.x*4;
  float4 te = *(const float4*)(timew + (size_t)fi*D + d0);
  float4 q0 = *(const float4*)(qbase + d0);
  float4 q1 = *(const float4*)(qbase + D + d0);
  float4 r0 = *(const float4*)(rolew + d0);
  float4 r1 = *(const float4*)(rolew + D + d0);
  float4 mi = *(const float4*)(maxini + (size_t)b*D + d0);
  const float invN = 1.0f/(float)N;
  float* o0 = q + (size_t)(2*b)*D + d0;
  float* o1 = q + (size_t)(2*b+1)*D + d0;
  o0[0] = macc[b*D+d0+0]*invN + q0.x + r0.x + te.x;
  o0[1] = macc[b*D+d0+1]*invN + q0.y + r0.y + te.y;
  o0[2] = macc[b*D+d0+2]*invN + q0.z + r0.z + te.z;
  o0[3] = macc[b*D+d0+3]*invN + q0.w + r0.w + te.w;
  o1[0] = mi.x + q1.x + r1.x + te.x;
  o1[1] = mi.y + q1.y + r1.y + te.y;
  o1[2] = mi.z + q1.z + r1.z + te.z;
  o1[3] = mi.w + q1.w + r1.w + te.w;
}

// ---------------- layernorm over D (64 rows), f32 in/out ----------------
__global__ __launch_bounds__(256) void ln_kernel(const float* __restrict__ in, float* __restrict__ outp,
    const float* __restrict__ g, const float* __restrict__ bb){
  int r = blockIdx.x;
  int d0 = threadIdx.x*4;
  float4 v = *(const float4*)(in + (size_t)r*D + d0);
  float s = v.x+v.y+v.z+v.w;
  float ss = v.x*v.x + v.y*v.y + v.z*v.z + v.w*v.w;
  #pragma unroll
  for(int o=1;o<64;o<<=1){ s += __shfl_xor(s,o); ss += __shfl_xor(ss,o); }
  __shared__ float as_[4], aq_[4];
  int w = threadIdx.x>>6;
  if((threadIdx.x&63)==0){ as_[w]=s; aq_[w]=ss; }
  __syncthreads();
  s = as_[0]+as_[1]+as_[2]+as_[3];
  ss = aq_[0]+aq_[1]+aq_[2]+aq_[3];
  float mean = s*(1.0f/D);
  float var = ss*(1.0f/D) - mean*mean;
  float rstd = rsqrtf(var + 1e-5f);
  float4 gv = *(const float4*)(g + d0);
  float4 bv = *(const float4*)(bb + d0);
  float4 ov;
  ov.x = (v.x-mean)*rstd*gv.x + bv.x;
  ov.y = (v.y-mean)*rstd*gv.y + bv.y;
  ov.z = (v.z-mean)*rstd*gv.z + bv.z;
  ov.w = (v.w-mean)*rstd*gv.w + bv.w;
  *(float4*)(outp + (size_t)r*D + d0) = ov;
}

// ------------- skinny GEMM: out[r,j] = op(sum_k in[r,k]*W_{t}[j,k] + bias[j]) -------------
__global__ __launch_bounds__(256) void gemm_skinny(const float* __restrict__ in,
    const float* __restrict__ W0, const float* __restrict__ W1,
    const float* __restrict__ b0_, const float* __restrict__ b1_,
    float* __restrict__ out, int K, int Dout, int mode){
  int t = blockIdx.y;
  int wv = threadIdx.x >> 6, lane = threadIdx.x & 63;
  int j0 = blockIdx.x*16 + wv*4;
  const float* W = t ? W1 : W0;
  const float* bias = t ? b1_ : b0_;
  for(int bg=0; bg<8; bg++){
    int r0 = bg*8 + t;
    float acc[4][4];
    #pragma unroll
    for(int i=0;i<4;i++)
      #pragma unroll
      for(int j=0;j<4;j++) acc[i][j]=0.f;
    for(int kb = lane*4; kb < K; kb += 256){
      float4 a[4];
      #pragma unroll
      for(int rr=0;rr<4;rr++) a[rr] = *(const float4*)(in + (size_t)(r0 + rr*2)*K + kb);
      #pragma unroll
      for(int c=0;c<4;c++){
        float4 w = *(const float4*)(W + (size_t)(j0+c)*K + kb);
        #pragma unroll
        for(int rr=0;rr<4;rr++)
          acc[rr][c] += a[rr].x*w.x + a[rr].y*w.y + a[rr].z*w.z + a[rr].w*w.w;
      }
    }
    #pragma unroll
    for(int rr=0;rr<4;rr++)
      #pragma unroll
      for(int c=0;c<4;c++){
        float v2 = acc[rr][c];
        #pragma unroll
        for(int o=1;o<64;o<<=1) v2 += __shfl_xor(v2,o);
        acc[rr][c]=v2;
      }
    if(lane==0){
      #pragma unroll
      for(int rr=0;rr<4;rr++){
        int r = r0 + rr*2;
        #pragma unroll
        for(int c=0;c<4;c++){
          float sum = acc[rr][c] + bias[j0+c];
          size_t oi = (size_t)r*Dout + j0 + c;
          if(mode==1) out[oi] += sum;
          else if(mode==2) out[oi] = 0.5f*sum*(1.0f + erff(sum*0.70710678118654752f));
          else out[oi] = sum;
        }
      }
    }
  }
}

// ---------------- tiny 2-token self attention (per batch) ----------------
__global__ __launch_bounds__(256) void sa_kernel(const float* __restrict__ qkv, float* __restrict__ o){
  int b = blockIdx.x;
  __shared__ float sh[2*3072];
  __shared__ float sS[16][2][2];
  __shared__ float sA[16][2][2];
  for(int idx=threadIdx.x; idx<2*3072; idx+=256)
    sh[idx] = qkv[(size_t)(2*b)*3072 + idx];
  __syncthreads();
  if(threadIdx.x < 64){
    int h = threadIdx.x>>2, t = (threadIdx.x>>1)&1, t2 = threadIdx.x&1;
    const float* qp_ = &sh[t*3072 + h*64];
    const float* kp_ = &sh[t2*3072 + 1024 + h*64];
    float s = 0.f;
    for(int d2=0; d2<64; d2++) s += qp_[d2]*kp_[d2];
    sS[h][t][t2] = s*0.125f;
  }
  __syncthreads();
  if(threadIdx.x < 32){
    int h = threadIdx.x>>1, t = threadIdx.x&1;
    float s0=sS[h][t][0], s1=sS[h][t][1];
    float mx = fmaxf(s0,s1);
    float e0=expf(s0-mx), e1=expf(s1-mx);
    float inv = 1.0f/(e0+e1);
    sA[h][t][0]=e0*inv; sA[h][t][1]=e1*inv;
  }
  __syncthreads();
  for(int idx=threadIdx.x; idx<2048; idx+=256){
    int t = idx>>10, c = idx&1023, h = c>>6;
    o[(size_t)(2*b+t)*D + c] = sA[h][t][0]*sh[2048+c] + sA[h][t][1]*sh[3072+2048+c];
  }
}

// ---------------- u[r,h,:] = bf16( (1/8) * sum_d qp[r,h*64+d] * Wk[h*64+d,:] ) ----------------
__global__ __launch_bounds__(256) void u_kernel(const float* __restrict__ qp,
    const float* __restrict__ Wcg, const float* __restrict__ Wcs, u16* __restrict__ u){
  int r = blockIdx.x; int t = r & 1; int h = blockIdx.y;
  const float* Wk = (t ? Wcs : Wcg) + (size_t)(D + h*64)*D;
  __shared__ float qs[64];
  if(threadIdx.x < 64) qs[threadIdx.x] = qp[(size_t)r*D + h*64 + threadIdx.x] * 0.125f;
  __syncthreads();
  int j0 = threadIdx.x*4;
  float a0=0.f,a1=0.f,a2=0.f,a3=0.f;
  for(int d=0; d<64; d++){
    float qd = qs[d];
    float4 w = *(const float4*)(Wk + (size_t)d*D + j0);
    a0 += qd*w.x; a1 += qd*w.y; a2 += qd*w.z; a3 += qd*w.w;
  }
  __bf16* up = (__bf16*)u + ((size_t)r*H + h)*D + j0;
  up[0]=(__bf16)a0; up[1]=(__bf16)a1; up[2]=(__bf16)a2; up[3]=(__bf16)a3;
}

// ---------------- fused single-query flash chunk, f32 source [fallback path] ----------------
template<int CH>
__global__ __launch_bounds__(256) void flash_kernel(const float* __restrict__ xsrc, int Nk,
    const u16* __restrict__ U, int t,
    float* __restrict__ pm, float* __restrict__ pl, float* __restrict__ py){
  constexpr int SS = CH + 4;
  constexpr int PS = CH + 8;
  __shared__ float S_s[16*SS];
  __shared__ __align__(16) u16 P_s[16*PS];
  int b = blockIdx.x, c = blockIdx.y;
  int tid = threadIdx.x, lane = tid&63, wv = tid>>6, quad = lane>>4, l15 = lane&15;
  const float* xb = xsrc + ((size_t)b*Nk + (size_t)c*CH)*D;
  const u16* ub = U + ((size_t)(2*b + t)*H)*D;
  for(int mt = wv; mt < CH/16; mt += 4){
    f32x4 acc = {0.f,0.f,0.f,0.f};
    const float* arow = xb + (size_t)(mt*16 + l15)*D + quad*8;
    const u16* ubase = ub + (size_t)l15*D + quad*8;
    #pragma unroll 4
    for(int kb=0; kb<D; kb+=32){
      float4 p0 = *(const float4*)(arow + kb);
      float4 p1 = *(const float4*)(arow + kb + 4);
      bf16x8 af;
      af[0]=(__bf16)p0.x; af[1]=(__bf16)p0.y; af[2]=(__bf16)p0.z; af[3]=(__bf16)p0.w;
      af[4]=(__bf16)p1.x; af[5]=(__bf16)p1.y; af[6]=(__bf16)p1.z; af[7]=(__bf16)p1.w;
      bf16x8 bfr = *(const bf16x8*)(ubase + kb);
      acc = __builtin_amdgcn_mfma_f32_16x16x32_bf16(af, bfr, acc, 0, 0, 0);
    }
    int tokb = mt*16 + quad*4;
    #pragma unroll
    for(int g2=0; g2<4; g2++) S_s[l15*SS + tokb + g2] = acc[g2];
  }
  __syncthreads();
  {
    int h = tid>>4, sub = tid&15;
    float mx = -1e30f;
    for(int k2=sub;k2<CH;k2+=16) mx = fmaxf(mx, S_s[h*SS+k2]);
    #pragma unroll
    for(int o2=1;o2<16;o2<<=1) mx = fmaxf(mx, __shfl_xor(mx,o2));
    float ls = 0.f;
    for(int k2=sub;k2<CH;k2+=16){
      float p = expf(S_s[h*SS+k2]-mx);
      ((__bf16*)P_s)[h*PS + k2] = (__bf16)p;
      ls += p;
    }
    #pragma unroll
    for(int o2=1;o2<16;o2<<=1) ls += __shfl_xor(ls,o2);
    if(sub==0){
      size_t pi = ((size_t)c*B + b)*H + h;
      pm[pi]=mx; pl[pi]=ls;
    }
  }
  __syncthreads();
  f32x4 acc[16];
  #pragma unroll
  for(int i=0;i<16;i++) acc[i] = (f32x4){0.f,0.f,0.f,0.f};
  int dbase = wv*256 + l15;
  for(int kb=0; kb<CH; kb+=32){
    bf16x8 af = *(const bf16x8*)(P_s + l15*PS + kb + quad*8);
    const float* col0 = xb + (size_t)(kb + quad*8)*D + dbase;
    #pragma unroll
    for(int nt=0; nt<16; nt++){
      bf16x8 bfr;
      #pragma unroll
      for(int j=0;j<8;j++) bfr[j] = (__bf16)col0[(size_t)j*D + nt*16];
      acc[nt] = __builtin_amdgcn_mfma_f32_16x16x32_bf16(af, bfr, acc[nt], 0, 0, 0);
    }
  }
  float* pyb = py + (((size_t)c*B + b)*H)*D;
  #pragma unroll
  for(int nt=0;nt<16;nt++){
    int d = wv*256 + nt*16 + l15;
    #pragma unroll
    for(int g2=0;g2<4;g2++){
      int h = quad*4+g2;
      pyb[(size_t)h*D + d] = acc[nt][g2];
    }
  }
}

// ---------------- fused single-query flash chunk, bf16 sources [fast path] ----------------
// XB: bf16 row-major [b][tok][d]  (phase-1 A-fragments: contiguous bf16x8 along d)
// XT: bf16 transposed [b][d][tok] (phase-2 B-fragments: contiguous bf16x8 along tok)
template<int CH>
__global__ __launch_bounds__(256) void flash2_kernel(const u16* __restrict__ XB,
    const u16* __restrict__ XT, int Nk, const u16* __restrict__ U, int t,
    float* __restrict__ pm, float* __restrict__ pl, float* __restrict__ py){
  constexpr int SS = CH + 4;
  constexpr int PS = CH + 8;
  __shared__ float S_s[16*SS];
  __shared__ __align__(16) u16 P_s[16*PS];
  int b = blockIdx.x, c = blockIdx.y;
  int tid = threadIdx.x, lane = tid&63, wv = tid>>6, quad = lane>>4, l15 = lane&15;
  const u16* xbb = XB + ((size_t)b*Nk + (size_t)c*CH)*D;   // [tok][d]
  const u16* xtb = XT + (size_t)b*D*Nk + (size_t)c*CH;     // [d][tok], row stride Nk
  const u16* ub  = U + ((size_t)(2*b + t)*H)*D;
  // phase 1: S[tok][h] = X(CHxD) . U^T
  for(int mt = wv; mt < CH/16; mt += 4){
    f32x4 acc = {0.f,0.f,0.f,0.f};
    const u16* arow  = xbb + (size_t)(mt*16 + l15)*D + quad*8;
    const u16* ubase = ub  + (size_t)l15*D + quad*8;
    #pragma unroll 8
    for(int kb=0; kb<D; kb+=32){
      bf16x8 af  = *(const bf16x8*)(arow + kb);
      bf16x8 bfr = *(const bf16x8*)(ubase + kb);
      acc = __builtin_amdgcn_mfma_f32_16x16x32_bf16(af, bfr, acc, 0, 0, 0);
    }
    int tokb = mt*16 + quad*4;
    #pragma unroll
    for(int g2=0; g2<4; g2++) S_s[l15*SS + tokb + g2] = acc[g2];
  }
  __syncthreads();
  // chunk-local softmax per head
  {
    int h = tid>>4, sub = tid&15;
    float mx = -1e30f;
    for(int k2=sub;k2<CH;k2+=16) mx = fmaxf(mx, S_s[h*SS+k2]);
    #pragma unroll
    for(int o2=1;o2<16;o2<<=1) mx = fmaxf(mx, __shfl_xor(mx,o2));
    float ls = 0.f;
    for(int k2=sub;k2<CH;k2+=16){
      float p = expf(S_s[h*SS+k2]-mx);
      ((__bf16*)P_s)[h*PS + k2] = (__bf16)p;
      ls += p;
    }
    #pragma unroll
    for(int o2=1;o2<16;o2<<=1) ls += __shfl_xor(ls,o2);
    if(sub==0){
      size_t pi = ((size_t)c*B + b)*H + h;
      pm[pi]=mx; pl[pi]=ls;
    }
  }
  __syncthreads();
  // phase 2: Ypart(16xD) = P(16xCH) . X(CHxD); wave owns 256 cols; B-frag from XT, vectorized
  f32x4 acc[16];
  #pragma unroll
  for(int i=0;i<16;i++) acc[i] = (f32x4){0.f,0.f,0.f,0.f};
  const u16* xtw = xtb + (size_t)(wv*256 + l15)*Nk;
  for(int kb=0; kb<CH; kb+=32){
    bf16x8 af = *(const bf16x8*)(P_s + l15*PS + kb + quad*8);
    #pragma unroll
    for(int nt=0; nt<16; nt++){
      bf16x8 bfr = *(const bf16x8*)(xtw + (size_t)(nt*16)*Nk + kb + quad*8);
      acc[nt] = __builtin_amdgcn_mfma_f32_16x16x32_bf16(af, bfr, acc[nt], 0, 0, 0);
    }
  }
  float* pyb = py + (((size_t)c*B + b)*H)*D;
  #pragma unroll
  for(int nt=0;nt<16;nt++){
    int d = wv*256 + nt*16 + l15;
    #pragma unroll
    for(int g2=0;g2<4;g2++){
      int h = quad*4+g2;
      pyb[(size_t)h*D + d] = acc[nt][g2];
    }
  }
}

// ---------------- cross-chunk softmax combine ----------------
__global__ __launch_bounds__(256) void combine_kernel(const float* __restrict__ pm, const float* __restrict__ pl,
    const float* __restrict__ py, float* __restrict__ y, int t, int C){
  int b = blockIdx.x, h = blockIdx.y, tid = threadIdx.x;
  float mx = -1e30f;
  for(int c2=0;c2<C;c2++) mx = fmaxf(mx, pm[((size_t)c2*B+b)*H + h]);
  __shared__ float wsh[16];
  if(tid < C) wsh[tid] = expf(pm[((size_t)tid*B+b)*H + h] - mx);
  __syncthreads();
  float L = 0.f;
  for(int c2=0;c2<C;c2++) L += wsh[c2]*pl[((size_t)c2*B+b)*H + h];
  float inv = 1.0f/L;
  for(int d = tid; d < D; d += 256){
    float a = 0.f;
    for(int c2=0;c2<C;c2++) a += wsh[c2]*py[(((size_t)c2*B+b)*H + h)*D + d];
    y[((size_t)(2*b+t)*H + h)*D + d] = a*inv;
  }
}

// ---------------- per-head V projection ----------------
__global__ __launch_bounds__(256) void headv_kernel(const float* __restrict__ y,
    const float* __restrict__ Wcg, const float* __restrict__ Wcs,
    const float* __restrict__ bcg, const float* __restrict__ bcs,
    float* __restrict__ o){
  int r = blockIdx.x, t = r&1, h = blockIdx.y;
  const float* Wv = (t?Wcs:Wcg) + (size_t)(2*D + h*64)*D;
  const float* bv = (t?bcs:bcg) + 2*D + h*64;
  __shared__ float ys[1024];
  int tid = threadIdx.x;
  *(float4*)&ys[tid*4] = *(const float4*)(y + ((size_t)r*H + h)*D + tid*4);
  __syncthreads();
  int wv2 = tid>>6, lane = tid&63;
  for(int dp = wv2; dp < 64; dp += 4){
    float a = 0.f;
    for(int jb = lane*4; jb < 1024; jb += 256){
      float4 w = *(const float4*)(Wv + (size_t)dp*D + jb);
      float4 yv = *(const float4*)&ys[jb];
      a += yv.x*w.x + yv.y*w.y + yv.z*w.z + yv.w*w.w;
    }
    #pragma unroll
    for(int o2=1;o2<64;o2<<=1) a += __shfl_xor(a,o2);
    if(lane==0) o[(size_t)r*D + h*64 + dp] = a + bv[dp];
  }
}

extern "C" void kernel_launch(void* const* d_in, const int* in_sizes, int n_in,
                              void* d_out, int out_size, void* d_ws, size_t ws_size,
                              hipStream_t stream){
  const float* frame  = (const float*)d_in[0];
  const float* sal    = (const float*)d_in[1];
  const float* maxini = (const float*)d_in[2];
  const float* qbase  = (const float*)d_in[3];
  const float* rolew  = (const float*)d_in[4];
  const float* timew  = (const float*)d_in[5];
  const float* ln1g   = (const float*)d_in[6];
  const float* ln1b   = (const float*)d_in[7];
  const float* sainw  = (const float*)d_in[8];
  const float* sainb  = (const float*)d_in[9];
  const float* saoutw = (const float*)d_in[10];
  const float* saoutb = (const float*)d_in[11];
  const float* ln2g   = (const float*)d_in[12];
  const float* ln2b   = (const float*)d_in[13];
  const float* cginw  = (const float*)d_in[14];
  const float* cginb  = (const float*)d_in[15];
  const float* cgoutw = (const float*)d_in[16];
  const float* cgoutb = (const float*)d_in[17];
  const float* csinw  = (const float*)d_in[18];
  const float* csinb  = (const float*)d_in[19];
  const float* csoutw = (const float*)d_in[20];
  const float* csoutb = (const float*)d_in[21];
  const float* ln3g   = (const float*)d_in[22];
  const float* ln3b   = (const float*)d_in[23];
  const float* ffnw1  = (const float*)d_in[24];
  const float* ffnb1  = (const float*)d_in[25];
  const float* ffnw2  = (const float*)d_in[26];
  const float* ffnb2  = (const float*)d_in[27];
  const float* outg   = (const float*)d_in[28];
  const float* outbb  = (const float*)d_in[29];
  const int* fidx     = (const int*)d_in[30];
  float* out = (float*)d_out;

  float* wsf = (float*)d_ws;
  float* MEAN = wsf + 0;         // B*D                    (32768)
  float* Q    = wsf + 32768;     // 64*D                   (65536)
  float* X    = wsf + 98304;     // 64*D
  float* QKV  = wsf + 163840;    // 64*3D                  (196608)
  float* O    = wsf + 360448;    // 64*D
  float* QP   = wsf + 425984;    // 64*D
  u16*   U    = (u16*)(wsf + 491520);  // 64*H*D bf16      (524288 floats)
  float* Y    = wsf + 1015808;   // 64*H*D                 (1048576)
  float* HH   = wsf + 2064384;   // 64*4D                  (262144)
  float* PM   = wsf + 2326528;   // 16*B*H                 (8192)
  float* PL   = wsf + 2334720;   // 16*B*H                 (8192)
  float* PY   = wsf + 2342912;   // 16*B*H*D               (8388608) -> base ends at 10731520 floats
  u16*   XBF  = (u16*)(wsf + 10731520);      // B*N*D bf16     (134217728 u16)
  u16*   XTF  = XBF + (size_t)B*N*D;         // B*D*N bf16
  u16*   XBS  = XTF + (size_t)B*N*D;         // B*KV*D bf16    (33554432 u16)
  u16*   XTS  = XBS + (size_t)B*KV*D;        // B*D*KV bf16
  // tiered fast paths by available workspace:
  //   frame-only fast: 10731520*4 + 2*B*N*D*2            = 579,796,992 B
  //   full fast:       + 2*B*KV*D*2                      = 714,014,720 B
  const bool fastF = ws_size >= 579796992ull;   // flash2 on frame
  const bool fastS = ws_size >= 714014720ull;   // flash2 on sal too

  hipMemsetAsync(MEAN, 0, (size_t)B*D*sizeof(float), stream);
  if(fastF){
    convt_kernel<<<dim3(N/64, D/64, B), 256, 0, stream>>>(frame, XBF, XTF, MEAN, N);
  }else{
    mean_kernel<<<dim3(B,32), 256, 0, stream>>>(frame, MEAN);
  }
  if(fastS){
    convt_kernel<<<dim3(KV/64, D/64, B), 256, 0, stream>>>(sal, XBS, XTS, nullptr, KV);
  }
  qinit_kernel<<<B, 256, 0, stream>>>(MEAN, maxini, qbase, rolew, timew, fidx, Q);

  for(int l=0; l<2; l++){
    size_t w3 = (size_t)l*3*D*D, w1 = (size_t)l*D*D, w4 = (size_t)l*4*D*D;
    size_t b3 = (size_t)l*3*D,   b1 = (size_t)l*D,   b4 = (size_t)l*4*D;

    ln_kernel<<<64,256,0,stream>>>(Q, X, ln1g+b1, ln1b+b1);
    gemm_skinny<<<dim3(3*D/16,2),256,0,stream>>>(X, sainw+w3, sainw+w3, sainb+b3, sainb+b3, QKV, D, 3*D, 0);
    sa_kernel<<<B,256,0,stream>>>(QKV, O);
    gemm_skinny<<<dim3(D/16,2),256,0,stream>>>(O, saoutw+w1, saoutw+w1, saoutb+b1, saoutb+b1, Q, D, D, 1);

    ln_kernel<<<64,256,0,stream>>>(Q, X, ln2g+b1, ln2b+b1);
    gemm_skinny<<<dim3(D/16,2),256,0,stream>>>(X, cginw+w3, csinw+w3, cginb+b3, csinb+b3, QP, D, D, 0);
    u_kernel<<<dim3(64,H),256,0,stream>>>(QP, cginw+w3, csinw+w3, U);

    if(fastF){
      flash2_kernel<256><<<dim3(B,16),256,0,stream>>>(XBF, XTF, N, U, 0, PM, PL, PY);
      combine_kernel<<<dim3(B,H),256,0,stream>>>(PM, PL, PY, Y, 0, 16);
    }else{
      flash_kernel<512><<<dim3(B,8),256,0,stream>>>(frame, N, U, 0, PM, PL, PY);
      combine_kernel<<<dim3(B,H),256,0,stream>>>(PM, PL, PY, Y, 0, 8);
    }
    if(fastS){
      flash2_kernel<64><<<dim3(B,16),256,0,stream>>>(XBS, XTS, KV, U, 1, PM, PL, PY);
      combine_kernel<<<dim3(B,H),256,0,stream>>>(PM, PL, PY, Y, 1, 16);
    }else{
      flash_kernel<128><<<dim3(B,8),256,0,stream>>>(sal, KV, U, 1, PM, PL, PY);
      combine_kernel<<<dim3(B,H),256,0,stream>>>(PM, PL, PY, Y, 1, 8);
    }

    headv_kernel<<<dim3(64,H),256,0,stream>>>(Y, cginw+w3, csinw+w3, cginb+b3, csinb+b3, O);
    gemm_skinny<<<dim3(D/16,2),256,0,stream>>>(O, cgoutw+w1, csoutw+w1, cgoutb+b1, csoutb+b1, Q, D, D, 1);

    ln_kernel<<<64,256,0,stream>>>(Q, X, ln3g+b1, ln3b+b1);
    gemm_skinny<<<dim3(4*D/16,2),256,0,stream>>>(X, ffnw1+w4, ffnw1+w4, ffnb1+b4, ffnb1+b4, HH, D, 4*D, 2);
    gemm_skinny<<<dim3(D/16,2),256,0,stream>>>(HH, ffnw2+w4, ffnw2+w4, ffnb2+b1, ffnb2+b1, Q, 4*D, D, 1);
  }
  ln_kernel<<<64,256,0,stream>>>(Q, out, outg, outbb);
}

// Round 13
// 2292.872 us; speedup vs baseline: 1.0283x; 1.0283x over previous
//
#include <hip/hip_runtime.h>

typedef unsigned short u16;
typedef __bf16 bf16x8 __attribute__((ext_vector_type(8)));
typedef float  f32x4  __attribute__((ext_vector_type(4)));

static constexpr int B = 32, N = 4096, KV = 1024, D = 1024, H = 16, MAXF = 4096;

// ---------------- mean over frame tokens (f32 atomic accumulate) [fallback path] ----------------
__global__ __launch_bounds__(256) void mean_kernel(const float* __restrict__ x, float* __restrict__ macc){
  int b = blockIdx.x, ch = blockIdx.y;
  int d0 = threadIdx.x*4;
  const float* p = x + ((size_t)b*N + (size_t)ch*128)*D + d0;
  float a0=0.f,a1=0.f,a2=0.f,a3=0.f;
  for(int k=0;k<128;k++){
    float4 v = *(const float4*)(p + (size_t)k*D);
    a0 += v.x; a1 += v.y; a2 += v.z; a3 += v.w;
  }
  atomicAdd(&macc[b*D + d0 + 0], a0);
  atomicAdd(&macc[b*D + d0 + 1], a1);
  atomicAdd(&macc[b*D + d0 + 2], a2);
  atomicAdd(&macc[b*D + d0 + 3], a3);
}

// ------- convert f32 [b][tok][d] -> bf16 row-major XB and bf16 transposed XT [b][d][tok] -------
__global__ __launch_bounds__(256) void convt_kernel(const float* __restrict__ x,
    u16* __restrict__ xb, u16* __restrict__ xt, float* __restrict__ macc, int Nk){
  int b  = blockIdx.z;
  int t0 = blockIdx.x*64, d0 = blockIdx.y*64;
  __shared__ u16 tile[64][70];
  __shared__ float rsum[16][64];
  int tid = threadIdx.x;
  int rr = tid>>4, c4 = (tid&15)*4;
  const float* src = x  + ((size_t)b*Nk + t0)*D + d0;
  u16*         xbp = xb + ((size_t)b*Nk + t0)*D + d0;
  float s0=0.f,s1=0.f,s2=0.f,s3=0.f;
  for(int it=0; it<4; it++){
    int r = rr + it*16;
    float4 v = *(const float4*)(src + (size_t)r*D + c4);
    s0+=v.x; s1+=v.y; s2+=v.z; s3+=v.w;
    __bf16 e0=(__bf16)v.x, e1=(__bf16)v.y, e2=(__bf16)v.z, e3=(__bf16)v.w;
    u16 u0=*(u16*)&e0, u1=*(u16*)&e1, u2=*(u16*)&e2, u3=*(u16*)&e3;
    tile[r][c4+0]=u0; tile[r][c4+1]=u1; tile[r][c4+2]=u2; tile[r][c4+3]=u3;
    ushort4 w4; w4.x=u0; w4.y=u1; w4.z=u2; w4.w=u3;
    *(ushort4*)(xbp + (size_t)r*D + c4) = w4;
  }
  if(macc){
    rsum[rr][c4+0]=s0; rsum[rr][c4+1]=s1; rsum[rr][c4+2]=s2; rsum[rr][c4+3]=s3;
  }
  __syncthreads();
  u16* xtp = xt + ((size_t)b*D + d0)*Nk + t0;
  for(int it=0; it<4; it++){
    int dr = rr + it*16;
    ushort4 w4;
    w4.x = tile[c4+0][dr]; w4.y = tile[c4+1][dr];
    w4.z = tile[c4+2][dr]; w4.w = tile[c4+3][dr];
    *(ushort4*)(xtp + (size_t)dr*Nk + c4) = w4;
  }
  if(macc && tid < 64){
    float s = 0.f;
    #pragma unroll
    for(int i2=0;i2<16;i2++) s += rsum[i2][tid];
    atomicAdd(&macc[(size_t)b*D + d0 + tid], s);
  }
}

// ---------------- q init ----------------
__global__ __launch_bounds__(256) void qinit_kernel(const float* __restrict__ macc,
    const float* __restrict__ maxini, const float* __restrict__ qbase, const float* __restrict__ rolew,
    const float* __restrict__ timew, const int* __restrict__ fidx, float* __restrict__ q){
  int b = blockIdx.x;
  int fi = fidx[b]; fi = fi < 0 ? 0 : (fi > MAXF-1 ? MAXF-1 : fi);
  int d0 = threadIdx.x*4;
  float4 te = *(const float4*)(timew + (size_t)fi*D + d0);
  float4 q0 = *(const float4*)(qbase + d0);
  float4 q1 = *(const float4*)(qbase + D + d0);
  float4 r0 = *(const float4*)(rolew + d0);
  float4 r1 = *(const float4*)(rolew + D + d0);
  float4 mi = *(const float4*)(maxini + (size_t)b*D + d0);
  const float invN = 1.0f/(float)N;
  float* o0 = q + (size_t)(2*b)*D + d0;
  float* o1 = q + (size_t)(2*b+1)*D + d0;
  o0[0] = macc[b*D+d0+0]*invN + q0.x + r0.x + te.x;
  o0[1] = macc[b*D+d0+1]*invN + q0.y + r0.y + te.y;
  o0[2] = macc[b*D+d0+2]*invN + q0.z + r0.z + te.z;
  o0[3] = macc[b*D+d0+3]*invN + q0.w + r0.w + te.w;
  o1[0] = mi.x + q1.x + r1.x + te.x;
  o1[1] = mi.y + q1.y + r1.y + te.y;
  o1[2] = mi.z + q1.z + r1.z + te.z;
  o1[3] = mi.w + q1.w + r1.w + te.w;
}

// ---------------- layernorm over D (64 rows), f32 in/out ----------------
__global__ __launch_bounds__(256) void ln_kernel(const float* __restrict__ in, float* __restrict__ outp,
    const float* __restrict__ g, const float* __restrict__ bb){
  int r = blockIdx.x;
  int d0 = threadIdx.x*4;
  float4 v = *(const float4*)(in + (size_t)r*D + d0);
  float s = v.x+v.y+v.z+v.w;
  float ss = v.x*v.x + v.y*v.y + v.z*v.z + v.w*v.w;
  #pragma unroll
  for(int o=1;o<64;o<<=1){ s += __shfl_xor(s,o); ss += __shfl_xor(ss,o); }
  __shared__ float as_[4], aq_[4];
  int w = threadIdx.x>>6;
  if((threadIdx.x&63)==0){ as_[w]=s; aq_[w]=ss; }
  __syncthreads();
  s = as_[0]+as_[1]+as_[2]+as_[3];
  ss = aq_[0]+aq_[1]+aq_[2]+aq_[3];
  float mean = s*(1.0f/D);
  float var = ss*(1.0f/D) - mean*mean;
  float rstd = rsqrtf(var + 1e-5f);
  float4 gv = *(const float4*)(g + d0);
  float4 bv = *(const float4*)(bb + d0);
  float4 ov;
  ov.x = (v.x-mean)*rstd*gv.x + bv.x;
  ov.y = (v.y-mean)*rstd*gv.y + bv.y;
  ov.z = (v.z-mean)*rstd*gv.z + bv.z;
  ov.w = (v.w-mean)*rstd*gv.w + bv.w;
  *(float4*)(outp + (size_t)r*D + d0) = ov;
}

// ------------- skinny GEMM: out[r,j] = op(sum_k in[r,k]*W_{t}[j,k] + bias[j]) -------------
__global__ __launch_bounds__(256) void gemm_skinny(const float* __restrict__ in,
    const float* __restrict__ W0, const float* __restrict__ W1,
    const float* __restrict__ b0_, const float* __restrict__ b1_,
    float* __restrict__ out, int K, int Dout, int mode){
  int t = blockIdx.y;
  int wv = threadIdx.x >> 6, lane = threadIdx.x & 63;
  int j0 = blockIdx.x*16 + wv*4;
  const float* W = t ? W1 : W0;
  const float* bias = t ? b1_ : b0_;
  for(int bg=0; bg<8; bg++){
    int r0 = bg*8 + t;
    float acc[4][4];
    #pragma unroll
    for(int i=0;i<4;i++)
      #pragma unroll
      for(int j=0;j<4;j++) acc[i][j]=0.f;
    for(int kb = lane*4; kb < K; kb += 256){
      float4 a[4];
      #pragma unroll
      for(int rr=0;rr<4;rr++) a[rr] = *(const float4*)(in + (size_t)(r0 + rr*2)*K + kb);
      #pragma unroll
      for(int c=0;c<4;c++){
        float4 w = *(const float4*)(W + (size_t)(j0+c)*K + kb);
        #pragma unroll
        for(int rr=0;rr<4;rr++)
          acc[rr][c] += a[rr].x*w.x + a[rr].y*w.y + a[rr].z*w.z + a[rr].w*w.w;
      }
    }
    #pragma unroll
    for(int rr=0;rr<4;rr++)
      #pragma unroll
      for(int c=0;c<4;c++){
        float v2 = acc[rr][c];
        #pragma unroll
        for(int o=1;o<64;o<<=1) v2 += __shfl_xor(v2,o);
        acc[rr][c]=v2;
      }
    if(lane==0){
      #pragma unroll
      for(int rr=0;rr<4;rr++){
        int r = r0 + rr*2;
        #pragma unroll
        for(int c=0;c<4;c++){
          float sum = acc[rr][c] + bias[j0+c];
          size_t oi = (size_t)r*Dout + j0 + c;
          if(mode==1) out[oi] += sum;
          else if(mode==2) out[oi] = 0.5f*sum*(1.0f + erff(sum*0.70710678118654752f));
          else out[oi] = sum;
        }
      }
    }
  }
}

// ---------------- tiny 2-token self attention (per batch) ----------------
__global__ __launch_bounds__(256) void sa_kernel(const float* __restrict__ qkv, float* __restrict__ o){
  int b = blockIdx.x;
  __shared__ float sh[2*3072];
  __shared__ float sS[16][2][2];
  __shared__ float sA[16][2][2];
  for(int idx=threadIdx.x; idx<2*3072; idx+=256)
    sh[idx] = qkv[(size_t)(2*b)*3072 + idx];
  __syncthreads();
  if(threadIdx.x < 64){
    int h = threadIdx.x>>2, t = (threadIdx.x>>1)&1, t2 = threadIdx.x&1;
    const float* qp_ = &sh[t*3072 + h*64];
    const float* kp_ = &sh[t2*3072 + 1024 + h*64];
    float s = 0.f;
    for(int d2=0; d2<64; d2++) s += qp_[d2]*kp_[d2];
    sS[h][t][t2] = s*0.125f;
  }
  __syncthreads();
  if(threadIdx.x < 32){
    int h = threadIdx.x>>1, t = threadIdx.x&1;
    float s0=sS[h][t][0], s1=sS[h][t][1];
    float mx = fmaxf(s0,s1);
    float e0=expf(s0-mx), e1=expf(s1-mx);
    float inv = 1.0f/(e0+e1);
    sA[h][t][0]=e0*inv; sA[h][t][1]=e1*inv;
  }
  __syncthreads();
  for(int idx=threadIdx.x; idx<2048; idx+=256){
    int t = idx>>10, c = idx&1023, h = c>>6;
    o[(size_t)(2*b+t)*D + c] = sA[h][t][0]*sh[2048+c] + sA[h][t][1]*sh[3072+2048+c];
  }
}

// ---------------- u[r,h,:] = bf16( (1/8) * sum_d qp[r,h*64+d] * Wk[h*64+d,:] ) ----------------
__global__ __launch_bounds__(256) void u_kernel(const float* __restrict__ qp,
    const float* __restrict__ Wcg, const float* __restrict__ Wcs, u16* __restrict__ u){
  int r = blockIdx.x; int t = r & 1; int h = blockIdx.y;
  const float* Wk = (t ? Wcs : Wcg) + (size_t)(D + h*64)*D;
  __shared__ float qs[64];
  if(threadIdx.x < 64) qs[threadIdx.x] = qp[(size_t)r*D + h*64 + threadIdx.x] * 0.125f;
  __syncthreads();
  int j0 = threadIdx.x*4;
  float a0=0.f,a1=0.f,a2=0.f,a3=0.f;
  for(int d=0; d<64; d++){
    float qd = qs[d];
    float4 w = *(const float4*)(Wk + (size_t)d*D + j0);
    a0 += qd*w.x; a1 += qd*w.y; a2 += qd*w.z; a3 += qd*w.w;
  }
  __bf16* up = (__bf16*)u + ((size_t)r*H + h)*D + j0;
  up[0]=(__bf16)a0; up[1]=(__bf16)a1; up[2]=(__bf16)a2; up[3]=(__bf16)a3;
}

// ---------------- fused single-query flash chunk, f32 source [fallback path] ----------------
template<int CH>
__global__ __launch_bounds__(256) void flash_kernel(const float* __restrict__ xsrc, int Nk,
    const u16* __restrict__ U, int t,
    float* __restrict__ pm, float* __restrict__ pl, float* __restrict__ py){
  constexpr int SS = CH + 4;
  constexpr int PS = CH + 8;
  __shared__ float S_s[16*SS];
  __shared__ __align__(16) u16 P_s[16*PS];
  int b = blockIdx.x, c = blockIdx.y;
  int tid = threadIdx.x, lane = tid&63, wv = tid>>6, quad = lane>>4, l15 = lane&15;
  const float* xb = xsrc + ((size_t)b*Nk + (size_t)c*CH)*D;
  const u16* ub = U + ((size_t)(2*b + t)*H)*D;
  for(int mt = wv; mt < CH/16; mt += 4){
    f32x4 acc = {0.f,0.f,0.f,0.f};
    const float* arow = xb + (size_t)(mt*16 + l15)*D + quad*8;
    const u16* ubase = ub + (size_t)l15*D + quad*8;
    #pragma unroll 4
    for(int kb=0; kb<D; kb+=32){
      float4 p0 = *(const float4*)(arow + kb);
      float4 p1 = *(const float4*)(arow + kb + 4);
      bf16x8 af;
      af[0]=(__bf16)p0.x; af[1]=(__bf16)p0.y; af[2]=(__bf16)p0.z; af[3]=(__bf16)p0.w;
      af[4]=(__bf16)p1.x; af[5]=(__bf16)p1.y; af[6]=(__bf16)p1.z; af[7]=(__bf16)p1.w;
      bf16x8 bfr = *(const bf16x8*)(ubase + kb);
      acc = __builtin_amdgcn_mfma_f32_16x16x32_bf16(af, bfr, acc, 0, 0, 0);
    }
    int tokb = mt*16 + quad*4;
    #pragma unroll
    for(int g2=0; g2<4; g2++) S_s[l15*SS + tokb + g2] = acc[g2];
  }
  __syncthreads();
  {
    int h = tid>>4, sub = tid&15;
    float mx = -1e30f;
    for(int k2=sub;k2<CH;k2+=16) mx = fmaxf(mx, S_s[h*SS+k2]);
    #pragma unroll
    for(int o2=1;o2<16;o2<<=1) mx = fmaxf(mx, __shfl_xor(mx,o2));
    float ls = 0.f;
    for(int k2=sub;k2<CH;k2+=16){
      float p = expf(S_s[h*SS+k2]-mx);
      ((__bf16*)P_s)[h*PS + k2] = (__bf16)p;
      ls += p;
    }
    #pragma unroll
    for(int o2=1;o2<16;o2<<=1) ls += __shfl_xor(ls,o2);
    if(sub==0){
      size_t pi = ((size_t)c*B + b)*H + h;
      pm[pi]=mx; pl[pi]=ls;
    }
  }
  __syncthreads();
  f32x4 acc[16];
  #pragma unroll
  for(int i=0;i<16;i++) acc[i] = (f32x4){0.f,0.f,0.f,0.f};
  int dbase = wv*256 + l15;
  for(int kb=0; kb<CH; kb+=32){
    bf16x8 af = *(const bf16x8*)(P_s + l15*PS + kb + quad*8);
    const float* col0 = xb + (size_t)(kb + quad*8)*D + dbase;
    #pragma unroll
    for(int nt=0; nt<16; nt++){
      bf16x8 bfr;
      #pragma unroll
      for(int j=0;j<8;j++) bfr[j] = (__bf16)col0[(size_t)j*D + nt*16];
      acc[nt] = __builtin_amdgcn_mfma_f32_16x16x32_bf16(af, bfr, acc[nt], 0, 0, 0);
    }
  }
  float* pyb = py + (((size_t)c*B + b)*H)*D;
  #pragma unroll
  for(int nt=0;nt<16;nt++){
    int d = wv*256 + nt*16 + l15;
    #pragma unroll
    for(int g2=0;g2<4;g2++){
      int h = quad*4+g2;
      pyb[(size_t)h*D + d] = acc[nt][g2];
    }
  }
}

// ---------------- flash chunk, bf16 sources, 8-wave blocks [fast path] ----------------
// 512 threads: phase2 per-wave = 128 cols -> acc[8] (32 VGPR) -> high occupancy.
template<int CH>
__global__ __launch_bounds__(512) void flash3_kernel(const u16* __restrict__ XB,
    const u16* __restrict__ XT, int Nk, const u16* __restrict__ U, int t,
    float* __restrict__ pm, float* __restrict__ pl, float* __restrict__ py){
  constexpr int SS = CH + 4;
  constexpr int PS = CH + 8;
  __shared__ float S_s[16*SS];
  __shared__ __align__(16) u16 P_s[16*PS];
  int b = blockIdx.x, c = blockIdx.y;
  int tid = threadIdx.x, lane = tid&63, wv = tid>>6, quad = lane>>4, l15 = lane&15;
  const u16* xbb = XB + ((size_t)b*Nk + (size_t)c*CH)*D;   // [tok][d]
  const u16* xtb = XT + (size_t)b*D*Nk + (size_t)c*CH;     // [d][tok], row stride Nk
  const u16* ub  = U + ((size_t)(2*b + t)*H)*D;
  // phase 1: S[tok][h] = X(CHxD) . U^T  (8 waves cover CH/16 tiles)
  for(int mt = wv; mt < CH/16; mt += 8){
    f32x4 acc = {0.f,0.f,0.f,0.f};
    const u16* arow  = xbb + (size_t)(mt*16 + l15)*D + quad*8;
    const u16* ubase = ub  + (size_t)l15*D + quad*8;
    #pragma unroll 8
    for(int kb=0; kb<D; kb+=32){
      bf16x8 af  = *(const bf16x8*)(arow + kb);
      bf16x8 bfr = *(const bf16x8*)(ubase + kb);
      acc = __builtin_amdgcn_mfma_f32_16x16x32_bf16(af, bfr, acc, 0, 0, 0);
    }
    int tokb = mt*16 + quad*4;
    #pragma unroll
    for(int g2=0; g2<4; g2++) S_s[l15*SS + tokb + g2] = acc[g2];
  }
  __syncthreads();
  // chunk-local softmax per head (32 threads per head, 512 threads total)
  {
    int h = tid>>5, sub = tid&31;
    float mx = -1e30f;
    for(int k2=sub;k2<CH;k2+=32) mx = fmaxf(mx, S_s[h*SS+k2]);
    #pragma unroll
    for(int o2=1;o2<32;o2<<=1) mx = fmaxf(mx, __shfl_xor(mx,o2));
    float ls = 0.f;
    for(int k2=sub;k2<CH;k2+=32){
      float p = expf(S_s[h*SS+k2]-mx);
      ((__bf16*)P_s)[h*PS + k2] = (__bf16)p;
      ls += p;
    }
    #pragma unroll
    for(int o2=1;o2<32;o2<<=1) ls += __shfl_xor(ls,o2);
    if(sub==0){
      size_t pi = ((size_t)c*B + b)*H + h;
      pm[pi]=mx; pl[pi]=ls;
    }
  }
  __syncthreads();
  // phase 2: Ypart(16xD) = P(16xCH) . X(CHxD); each wave owns 128 cols
  f32x4 acc[8];
  #pragma unroll
  for(int i=0;i<8;i++) acc[i] = (f32x4){0.f,0.f,0.f,0.f};
  const u16* xtw = xtb + (size_t)(wv*128 + l15)*Nk;
  for(int kb=0; kb<CH; kb+=32){
    bf16x8 af = *(const bf16x8*)(P_s + l15*PS + kb + quad*8);
    #pragma unroll
    for(int nt=0; nt<8; nt++){
      bf16x8 bfr = *(const bf16x8*)(xtw + (size_t)(nt*16)*Nk + kb + quad*8);
      acc[nt] = __builtin_amdgcn_mfma_f32_16x16x32_bf16(af, bfr, acc[nt], 0, 0, 0);
    }
  }
  float* pyb = py + (((size_t)c*B + b)*H)*D;
  #pragma unroll
  for(int nt=0;nt<8;nt++){
    int d = wv*128 + nt*16 + l15;
    #pragma unroll
    for(int g2=0;g2<4;g2++){
      int h = quad*4+g2;
      pyb[(size_t)h*D + d] = acc[nt][g2];
    }
  }
}

// ---------------- cross-chunk softmax combine (single t) [fallback] ----------------
__global__ __launch_bounds__(256) void combine_kernel(const float* __restrict__ pm, const float* __restrict__ pl,
    const float* __restrict__ py, float* __restrict__ y, int t, int C){
  int b = blockIdx.x, h = blockIdx.y, tid = threadIdx.x;
  float mx = -1e30f;
  for(int c2=0;c2<C;c2++) mx = fmaxf(mx, pm[((size_t)c2*B+b)*H + h]);
  __shared__ float wsh[16];
  if(tid < C) wsh[tid] = expf(pm[((size_t)tid*B+b)*H + h] - mx);
  __syncthreads();
  float L = 0.f;
  for(int c2=0;c2<C;c2++) L += wsh[c2]*pl[((size_t)c2*B+b)*H + h];
  float inv = 1.0f/L;
  for(int d = tid; d < D; d += 256){
    float a = 0.f;
    for(int c2=0;c2<C;c2++) a += wsh[c2]*py[(((size_t)c2*B+b)*H + h)*D + d];
    y[((size_t)(2*b+t)*H + h)*D + d] = a*inv;
  }
}

// ---------------- fused combine for both tokens (t=blockIdx.z) [fast path] ----------------
__global__ __launch_bounds__(256) void combine2_kernel(
    const float* __restrict__ pm0, const float* __restrict__ pl0, const float* __restrict__ py0,
    const float* __restrict__ pm1, const float* __restrict__ pl1, const float* __restrict__ py1,
    float* __restrict__ y){
  int b = blockIdx.x, h = blockIdx.y, t = blockIdx.z, tid = threadIdx.x;
  const float* pm = t ? pm1 : pm0;
  const float* pl = t ? pl1 : pl0;
  const float* py = t ? py1 : py0;
  int C = t ? 8 : 16;
  float mx = -1e30f;
  for(int c2=0;c2<C;c2++) mx = fmaxf(mx, pm[((size_t)c2*B+b)*H + h]);
  __shared__ float wsh[16];
  if(tid < C) wsh[tid] = expf(pm[((size_t)tid*B+b)*H + h] - mx);
  __syncthreads();
  float L = 0.f;
  for(int c2=0;c2<C;c2++) L += wsh[c2]*pl[((size_t)c2*B+b)*H + h];
  float inv = 1.0f/L;
  for(int d = tid; d < D; d += 256){
    float a = 0.f;
    for(int c2=0;c2<C;c2++) a += wsh[c2]*py[(((size_t)c2*B+b)*H + h)*D + d];
    y[((size_t)(2*b+t)*H + h)*D + d] = a*inv;
  }
}

// ---------------- per-head V projection ----------------
__global__ __launch_bounds__(256) void headv_kernel(const float* __restrict__ y,
    const float* __restrict__ Wcg, const float* __restrict__ Wcs,
    const float* __restrict__ bcg, const float* __restrict__ bcs,
    float* __restrict__ o){
  int r = blockIdx.x, t = r&1, h = blockIdx.y;
  const float* Wv = (t?Wcs:Wcg) + (size_t)(2*D + h*64)*D;
  const float* bv = (t?bcs:bcg) + 2*D + h*64;
  __shared__ float ys[1024];
  int tid = threadIdx.x;
  *(float4*)&ys[tid*4] = *(const float4*)(y + ((size_t)r*H + h)*D + tid*4);
  __syncthreads();
  int wv2 = tid>>6, lane = tid&63;
  for(int dp = wv2; dp < 64; dp += 4){
    float a = 0.f;
    for(int jb = lane*4; jb < 1024; jb += 256){
      float4 w = *(const float4*)(Wv + (size_t)dp*D + jb);
      float4 yv = *(const float4*)&ys[jb];
      a += yv.x*w.x + yv.y*w.y + yv.z*w.z + yv.w*w.w;
    }
    #pragma unroll
    for(int o2=1;o2<64;o2<<=1) a += __shfl_xor(a,o2);
    if(lane==0) o[(size_t)r*D + h*64 + dp] = a + bv[dp];
  }
}

extern "C" void kernel_launch(void* const* d_in, const int* in_sizes, int n_in,
                              void* d_out, int out_size, void* d_ws, size_t ws_size,
                              hipStream_t stream){
  const float* frame  = (const float*)d_in[0];
  const float* sal    = (const float*)d_in[1];
  const float* maxini = (const float*)d_in[2];
  const float* qbase  = (const float*)d_in[3];
  const float* rolew  = (const float*)d_in[4];
  const float* timew  = (const float*)d_in[5];
  const float* ln1g   = (const float*)d_in[6];
  const float* ln1b   = (const float*)d_in[7];
  const float* sainw  = (const float*)d_in[8];
  const float* sainb  = (const float*)d_in[9];
  const float* saoutw = (const float*)d_in[10];
  const float* saoutb = (const float*)d_in[11];
  const float* ln2g   = (const float*)d_in[12];
  const float* ln2b   = (const float*)d_in[13];
  const float* cginw  = (const float*)d_in[14];
  const float* cginb  = (const float*)d_in[15];
  const float* cgoutw = (const float*)d_in[16];
  const float* cgoutb = (const float*)d_in[17];
  const float* csinw  = (const float*)d_in[18];
  const float* csinb  = (const float*)d_in[19];
  const float* csoutw = (const float*)d_in[20];
  const float* csoutb = (const float*)d_in[21];
  const float* ln3g   = (const float*)d_in[22];
  const float* ln3b   = (const float*)d_in[23];
  const float* ffnw1  = (const float*)d_in[24];
  const float* ffnb1  = (const float*)d_in[25];
  const float* ffnw2  = (const float*)d_in[26];
  const float* ffnb2  = (const float*)d_in[27];
  const float* outg   = (const float*)d_in[28];
  const float* outbb  = (const float*)d_in[29];
  const int* fidx     = (const int*)d_in[30];
  float* out = (float*)d_out;

  float* wsf = (float*)d_ws;
  float* MEAN = wsf + 0;         // B*D
  float* Q    = wsf + 32768;     // 64*D
  float* X    = wsf + 98304;     // 64*D
  float* QKV  = wsf + 163840;    // 64*3D
  float* O    = wsf + 360448;    // 64*D
  float* QP   = wsf + 425984;    // 64*D
  u16*   U    = (u16*)(wsf + 491520);  // 64*H*D bf16
  float* Y    = wsf + 1015808;   // 64*H*D
  float* HH   = wsf + 2064384;   // 64*4D
  float* PM   = wsf + 2326528;   // 16*B*H
  float* PL   = wsf + 2334720;   // 16*B*H
  float* PY   = wsf + 2342912;   // 16*B*H*D (8388608) -> base ends at 10731520 floats
  u16*   XBF  = (u16*)(wsf + 10731520);      // B*N*D bf16
  u16*   XTF  = XBF + (size_t)B*N*D;         // B*D*N bf16
  u16*   XBS  = XTF + (size_t)B*N*D;         // B*KV*D bf16
  u16*   XTS  = XBS + (size_t)B*KV*D;        // B*D*KV bf16
  float* PM2  = wsf + 178503680; // 8*B*H   (after XTS: 10731520 + 167772160 floats)
  float* PL2  = wsf + 178507776; // 8*B*H
  float* PY2  = wsf + 178511872; // 8*B*H*D (4194304) -> ends 182706176 floats = 730,824,704 B
  // tiers by workspace:
  const bool fastF = ws_size >= 579796992ull;   // flash3 on frame
  const bool fastS = ws_size >= 730824704ull;   // flash3 on sal + fused combine

  hipMemsetAsync(MEAN, 0, (size_t)B*D*sizeof(float), stream);
  if(fastF){
    convt_kernel<<<dim3(N/64, D/64, B), 256, 0, stream>>>(frame, XBF, XTF, MEAN, N);
  }else{
    mean_kernel<<<dim3(B,32), 256, 0, stream>>>(frame, MEAN);
  }
  if(fastS){
    convt_kernel<<<dim3(KV/64, D/64, B), 256, 0, stream>>>(sal, XBS, XTS, nullptr, KV);
  }
  qinit_kernel<<<B, 256, 0, stream>>>(MEAN, maxini, qbase, rolew, timew, fidx, Q);

  for(int l=0; l<2; l++){
    size_t w3 = (size_t)l*3*D*D, w1 = (size_t)l*D*D, w4 = (size_t)l*4*D*D;
    size_t b3 = (size_t)l*3*D,   b1 = (size_t)l*D,   b4 = (size_t)l*4*D;

    ln_kernel<<<64,256,0,stream>>>(Q, X, ln1g+b1, ln1b+b1);
    gemm_skinny<<<dim3(3*D/16,2),256,0,stream>>>(X, sainw+w3, sainw+w3, sainb+b3, sainb+b3, QKV, D, 3*D, 0);
    sa_kernel<<<B,256,0,stream>>>(QKV, O);
    gemm_skinny<<<dim3(D/16,2),256,0,stream>>>(O, saoutw+w1, saoutw+w1, saoutb+b1, saoutb+b1, Q, D, D, 1);

    ln_kernel<<<64,256,0,stream>>>(Q, X, ln2g+b1, ln2b+b1);
    gemm_skinny<<<dim3(D/16,2),256,0,stream>>>(X, cginw+w3, csinw+w3, cginb+b3, csinb+b3, QP, D, D, 0);
    u_kernel<<<dim3(64,H),256,0,stream>>>(QP, cginw+w3, csinw+w3, U);

    if(fastS){
      flash3_kernel<256><<<dim3(B,16),512,0,stream>>>(XBF, XTF, N, U, 0, PM, PL, PY);
      flash3_kernel<128><<<dim3(B,8),512,0,stream>>>(XBS, XTS, KV, U, 1, PM2, PL2, PY2);
      combine2_kernel<<<dim3(B,H,2),256,0,stream>>>(PM, PL, PY, PM2, PL2, PY2, Y);
    }else if(fastF){
      flash3_kernel<256><<<dim3(B,16),512,0,stream>>>(XBF, XTF, N, U, 0, PM, PL, PY);
      combine_kernel<<<dim3(B,H),256,0,stream>>>(PM, PL, PY, Y, 0, 16);
      flash_kernel<128><<<dim3(B,8),256,0,stream>>>(sal, KV, U, 1, PM, PL, PY);
      combine_kernel<<<dim3(B,H),256,0,stream>>>(PM, PL, PY, Y, 1, 8);
    }else{
      flash_kernel<512><<<dim3(B,8),256,0,stream>>>(frame, N, U, 0, PM, PL, PY);
      combine_kernel<<<dim3(B,H),256,0,stream>>>(PM, PL, PY, Y, 0, 8);
      flash_kernel<128><<<dim3(B,8),256,0,stream>>>(sal, KV, U, 1, PM, PL, PY);
      combine_kernel<<<dim3(B,H),256,0,stream>>>(PM, PL, PY, Y, 1, 8);
    }

    headv_kernel<<<dim3(64,H),256,0,stream>>>(Y, cginw+w3, csinw+w3, cginb+b3, csinb+b3, O);
    gemm_skinny<<<dim3(D/16,2),256,0,stream>>>(O, cgoutw+w1, csoutw+w1, cgoutb+b1, csoutb+b1, Q, D, D, 1);

    ln_kernel<<<64,256,0,stream>>>(Q, X, ln3g+b1, ln3b+b1);
    gemm_skinny<<<dim3(4*D/16,2),256,0,stream>>>(X, ffnw1+w4, ffnw1+w4, ffnb1+b4, ffnb1+b4, HH, D, 4*D, 2);
    gemm_skinny<<<dim3(D/16,2),256,0,stream>>>(HH, ffnw2+w4, ffnw2+w4, ffnb2+b1, ffnb2+b1, Q, 4*D, D, 1);
  }
  ln_kernel<<<64,256,0,stream>>>(Q, out, outg, outbb);
}